// Round 1
// baseline (776.875 us; speedup 1.0000x reference)
//
#include <hip/hip_runtime.h>

#define DIM 64

// agg[i] = (1+eps_L) * x[i], vectorized float4
__global__ __launch_bounds__(256)
void init_agg_kernel(const float* __restrict__ x, const float* __restrict__ epsL,
                     float* __restrict__ agg, int n4) {
    int i = blockIdx.x * blockDim.x + threadIdx.x;
    if (i >= n4) return;
    float s = 1.0f + epsL[0];
    float4 v = reinterpret_cast<const float4*>(x)[i];
    v.x *= s; v.y *= s; v.z *= s; v.w *= s;
    reinterpret_cast<float4*>(agg)[i] = v;
}

// 16 threads per edge, each handles 4 floats: agg[dst] += relu(x[src] + ea)
__global__ __launch_bounds__(256)
void scatter_kernel(const float* __restrict__ x, const int* __restrict__ ei,
                    const float* __restrict__ ea, float* __restrict__ agg, int nE) {
    long gid = (long)blockIdx.x * blockDim.x + threadIdx.x;
    int e = (int)(gid >> 4);
    if (e >= nE) return;
    int d4 = (int)(gid & 15);
    int s = ei[e];
    int t = ei[nE + e];
    float4 m = reinterpret_cast<const float4*>(ea)[e * 16 + d4];
    float4 xv = reinterpret_cast<const float4*>(x)[(long)s * 16 + d4];
    float* dst = agg + (long)t * DIM + d4 * 4;
    unsafeAtomicAdd(dst + 0, fmaxf(m.x + xv.x, 0.0f));
    unsafeAtomicAdd(dst + 1, fmaxf(m.y + xv.y, 0.0f));
    unsafeAtomicAdd(dst + 2, fmaxf(m.z + xv.z, 0.0f));
    unsafeAtomicAdd(dst + 3, fmaxf(m.w + xv.w, 0.0f));
}

// io (= agg rows) -> relu(relu(io@W1+b1)@W2+b2), in place per node row.
// One wave per node; lane j owns output column j; shuffle-broadcast dot.
__global__ __launch_bounds__(256)
void mlp_kernel(const float* __restrict__ W1, const float* __restrict__ b1,
                const float* __restrict__ W2, const float* __restrict__ b2,
                float* __restrict__ io, int nNodes) {
    __shared__ float sW1[DIM * DIM];
    __shared__ float sW2[DIM * DIM];
    __shared__ float sb1[DIM];
    __shared__ float sb2[DIM];
    for (int i = threadIdx.x; i < DIM * DIM; i += blockDim.x) {
        sW1[i] = W1[i];
        sW2[i] = W2[i];
    }
    if (threadIdx.x < DIM) {
        sb1[threadIdx.x] = b1[threadIdx.x];
        sb2[threadIdx.x] = b2[threadIdx.x];
    }
    __syncthreads();
    const int lane = threadIdx.x & 63;
    const int wave = threadIdx.x >> 6;
    const int wavesPerBlock = blockDim.x >> 6;
    const int wavesTotal = gridDim.x * wavesPerBlock;
    for (int node = blockIdx.x * wavesPerBlock + wave; node < nNodes; node += wavesTotal) {
        float h0 = io[(long)node * DIM + lane];
        float acc = sb1[lane];
        #pragma unroll
        for (int k = 0; k < DIM; ++k) {
            acc = fmaf(__shfl(h0, k), sW1[k * DIM + lane], acc);
        }
        float h1 = fmaxf(acc, 0.0f);
        float acc2 = sb2[lane];
        #pragma unroll
        for (int k = 0; k < DIM; ++k) {
            acc2 = fmaf(__shfl(h1, k), sW2[k * DIM + lane], acc2);
        }
        io[(long)node * DIM + lane] = fmaxf(acc2, 0.0f);
    }
}

extern "C" void kernel_launch(void* const* d_in, const int* in_sizes, int n_in,
                              void* d_out, int out_size, void* d_ws, size_t ws_size,
                              hipStream_t stream) {
    const float* x   = (const float*)d_in[0];
    const int*   ei  = (const int*)d_in[1];
    const float* ea  = (const float*)d_in[2];
    const float* W1  = (const float*)d_in[3];
    const float* b1  = (const float*)d_in[4];
    const float* W2  = (const float*)d_in[5];
    const float* b2  = (const float*)d_in[6];
    const float* eps = (const float*)d_in[7];

    const int nNodes  = in_sizes[0] / DIM;
    const int nE      = in_sizes[1] / 2;
    const int nLayers = in_sizes[3] / (DIM * DIM);
    const int L       = nLayers - 1;   // only the last layer affects the output

    float* agg = (float*)d_out;        // d_out doubles as the agg buffer

    // 1) agg = (1+eps[L]) * x
    int n4 = nNodes * (DIM / 4);
    hipLaunchKernelGGL(init_agg_kernel, dim3((n4 + 255) / 256), dim3(256), 0, stream,
                       x, eps + L, agg, n4);

    // 2) scatter-add relu(x[src]+edge_attr) into agg[dst]
    long totalThreads = (long)nE * 16;
    int scatterBlocks = (int)((totalThreads + 255) / 256);
    hipLaunchKernelGGL(scatter_kernel, dim3(scatterBlocks), dim3(256), 0, stream,
                       x, ei, ea, agg, nE);

    // 3) in-place MLP of layer L
    hipLaunchKernelGGL(mlp_kernel, dim3(1024), dim3(256), 0, stream,
                       W1 + (long)L * DIM * DIM, b1 + (long)L * DIM,
                       W2 + (long)L * DIM * DIM, b2 + (long)L * DIM,
                       agg, nNodes);
}

// Round 2
// 354.675 us; speedup vs baseline: 2.1904x; 2.1904x over previous
//
#include <hip/hip_runtime.h>

#define DIM 64

// ---------------- CSR build ----------------

__global__ __launch_bounds__(256)
void count_kernel(const int* __restrict__ dst, int* __restrict__ counts, int nE) {
    int e = blockIdx.x * 256 + threadIdx.x;
    if (e < nE) atomicAdd(&counts[dst[e]], 1);
}

__global__ __launch_bounds__(1024)
void scan_kernel(const int* __restrict__ counts, int* __restrict__ rowStart,
                 int* __restrict__ cursor, int n) {
    __shared__ int part[1024];
    int t = threadIdx.x;
    int chunk = (n + 1023) >> 10;
    int beg = min(t * chunk, n);
    int end = min(beg + chunk, n);
    int s = 0;
    for (int i = beg; i < end; ++i) s += counts[i];
    part[t] = s;
    __syncthreads();
    for (int off = 1; off < 1024; off <<= 1) {
        int v = (t >= off) ? part[t - off] : 0;
        __syncthreads();
        part[t] += v;
        __syncthreads();
    }
    int run = (t == 0) ? 0 : part[t - 1];
    for (int i = beg; i < end; ++i) {
        rowStart[i] = run;
        cursor[i] = run;
        run += counts[i];
    }
    if (t == 0) rowStart[n] = part[1023];
}

__global__ __launch_bounds__(256)
void permute_kernel(const int* __restrict__ ei, int* __restrict__ cursor,
                    int2* __restrict__ perm, int nE) {
    int e = blockIdx.x * 256 + threadIdx.x;
    if (e >= nE) return;
    int s = ei[e];
    int t = ei[nE + e];
    int pos = atomicAdd(&cursor[t], 1);
    perm[pos] = make_int2(s, e);
}

// ---------------- fused gather + MLP ----------------
// One wave per node, lane d owns dim d. acc = (1+eps)*x[node] + sum relu(x[src]+ea[e]).
// Then h = relu(acc@W1+b1); out = relu(h@W2+b2) via lane-broadcast dots.
__global__ __launch_bounds__(256)
void gather_mlp_kernel(const float* __restrict__ x, const float* __restrict__ ea,
                       const int2* __restrict__ perm, const int* __restrict__ rowStart,
                       const float* __restrict__ epsL,
                       const float* __restrict__ W1, const float* __restrict__ b1,
                       const float* __restrict__ W2, const float* __restrict__ b2,
                       float* __restrict__ out, int nNodes) {
    __shared__ float sW1[DIM * DIM];
    __shared__ float sW2[DIM * DIM];
    __shared__ float sb1[DIM];
    __shared__ float sb2[DIM];
    for (int i = threadIdx.x; i < DIM * DIM; i += blockDim.x) {
        sW1[i] = W1[i];
        sW2[i] = W2[i];
    }
    if (threadIdx.x < DIM) {
        sb1[threadIdx.x] = b1[threadIdx.x];
        sb2[threadIdx.x] = b2[threadIdx.x];
    }
    __syncthreads();
    const int lane = threadIdx.x & 63;
    const int wave = threadIdx.x >> 6;
    const int wavesPerBlock = blockDim.x >> 6;
    const int wavesTotal = gridDim.x * wavesPerBlock;
    const float eps1 = 1.0f + epsL[0];
    for (int node = blockIdx.x * wavesPerBlock + wave; node < nNodes; node += wavesTotal) {
        int beg = rowStart[node];
        int end = rowStart[node + 1];
        float acc = eps1 * x[(long)node * DIM + lane];
        int j = beg;
        for (; j + 3 < end; j += 4) {
            int2 p0 = perm[j], p1 = perm[j + 1], p2 = perm[j + 2], p3 = perm[j + 3];
            float a0 = x[(long)p0.x * DIM + lane] + ea[(long)p0.y * DIM + lane];
            float a1 = x[(long)p1.x * DIM + lane] + ea[(long)p1.y * DIM + lane];
            float a2 = x[(long)p2.x * DIM + lane] + ea[(long)p2.y * DIM + lane];
            float a3 = x[(long)p3.x * DIM + lane] + ea[(long)p3.y * DIM + lane];
            acc += fmaxf(a0, 0.f) + fmaxf(a1, 0.f) + fmaxf(a2, 0.f) + fmaxf(a3, 0.f);
        }
        for (; j < end; ++j) {
            int2 p = perm[j];
            acc += fmaxf(x[(long)p.x * DIM + lane] + ea[(long)p.y * DIM + lane], 0.f);
        }
        float o1 = sb1[lane];
        #pragma unroll
        for (int k = 0; k < DIM; ++k) o1 = fmaf(__shfl(acc, k), sW1[k * DIM + lane], o1);
        float h = fmaxf(o1, 0.f);
        float o2 = sb2[lane];
        #pragma unroll
        for (int k = 0; k < DIM; ++k) o2 = fmaf(__shfl(h, k), sW2[k * DIM + lane], o2);
        out[(long)node * DIM + lane] = fmaxf(o2, 0.f);
    }
}

// ---------------- fallback (atomic) path, used only if ws too small ----------------

__global__ __launch_bounds__(256)
void init_agg_kernel(const float* __restrict__ x, const float* __restrict__ epsL,
                     float* __restrict__ agg, int n4) {
    int i = blockIdx.x * blockDim.x + threadIdx.x;
    if (i >= n4) return;
    float s = 1.0f + epsL[0];
    float4 v = reinterpret_cast<const float4*>(x)[i];
    v.x *= s; v.y *= s; v.z *= s; v.w *= s;
    reinterpret_cast<float4*>(agg)[i] = v;
}

__global__ __launch_bounds__(256)
void scatter_kernel(const float* __restrict__ x, const int* __restrict__ ei,
                    const float* __restrict__ ea, float* __restrict__ agg, int nE) {
    long gid = (long)blockIdx.x * blockDim.x + threadIdx.x;
    int e = (int)(gid >> 4);
    if (e >= nE) return;
    int d4 = (int)(gid & 15);
    int s = ei[e];
    int t = ei[nE + e];
    float4 m = reinterpret_cast<const float4*>(ea)[e * 16 + d4];
    float4 xv = reinterpret_cast<const float4*>(x)[(long)s * 16 + d4];
    float* dst = agg + (long)t * DIM + d4 * 4;
    unsafeAtomicAdd(dst + 0, fmaxf(m.x + xv.x, 0.0f));
    unsafeAtomicAdd(dst + 1, fmaxf(m.y + xv.y, 0.0f));
    unsafeAtomicAdd(dst + 2, fmaxf(m.z + xv.z, 0.0f));
    unsafeAtomicAdd(dst + 3, fmaxf(m.w + xv.w, 0.0f));
}

__global__ __launch_bounds__(256)
void mlp_kernel(const float* __restrict__ W1, const float* __restrict__ b1,
                const float* __restrict__ W2, const float* __restrict__ b2,
                float* __restrict__ io, int nNodes) {
    __shared__ float sW1[DIM * DIM];
    __shared__ float sW2[DIM * DIM];
    __shared__ float sb1[DIM];
    __shared__ float sb2[DIM];
    for (int i = threadIdx.x; i < DIM * DIM; i += blockDim.x) {
        sW1[i] = W1[i];
        sW2[i] = W2[i];
    }
    if (threadIdx.x < DIM) {
        sb1[threadIdx.x] = b1[threadIdx.x];
        sb2[threadIdx.x] = b2[threadIdx.x];
    }
    __syncthreads();
    const int lane = threadIdx.x & 63;
    const int wave = threadIdx.x >> 6;
    const int wavesPerBlock = blockDim.x >> 6;
    const int wavesTotal = gridDim.x * wavesPerBlock;
    for (int node = blockIdx.x * wavesPerBlock + wave; node < nNodes; node += wavesTotal) {
        float h0 = io[(long)node * DIM + lane];
        float acc = sb1[lane];
        #pragma unroll
        for (int k = 0; k < DIM; ++k) acc = fmaf(__shfl(h0, k), sW1[k * DIM + lane], acc);
        float h1 = fmaxf(acc, 0.0f);
        float acc2 = sb2[lane];
        #pragma unroll
        for (int k = 0; k < DIM; ++k) acc2 = fmaf(__shfl(h1, k), sW2[k * DIM + lane], acc2);
        io[(long)node * DIM + lane] = fmaxf(acc2, 0.0f);
    }
}

extern "C" void kernel_launch(void* const* d_in, const int* in_sizes, int n_in,
                              void* d_out, int out_size, void* d_ws, size_t ws_size,
                              hipStream_t stream) {
    const float* x   = (const float*)d_in[0];
    const int*   ei  = (const int*)d_in[1];
    const float* ea  = (const float*)d_in[2];
    const float* W1  = (const float*)d_in[3];
    const float* b1  = (const float*)d_in[4];
    const float* W2  = (const float*)d_in[5];
    const float* b2  = (const float*)d_in[6];
    const float* eps = (const float*)d_in[7];

    const int nNodes  = in_sizes[0] / DIM;
    const int nE      = in_sizes[1] / 2;
    const int nLayers = in_sizes[3] / (DIM * DIM);
    const int L       = nLayers - 1;   // only the last layer affects the output

    const float* W1L = W1 + (long)L * DIM * DIM;
    const float* b1L = b1 + (long)L * DIM;
    const float* W2L = W2 + (long)L * DIM * DIM;
    const float* b2L = b2 + (long)L * DIM;
    float* outp = (float*)d_out;

    // ws layout: cursor[int N] | rowStart[int N+1] | pad | perm[int2 E]
    size_t cursorOff = 0;
    size_t rowOff    = (size_t)nNodes * 4;
    size_t permOff   = ((rowOff + (size_t)(nNodes + 1) * 4 + 7) / 8) * 8;
    size_t needed    = permOff + (size_t)nE * 8;

    if (ws_size >= needed) {
        int*  cursor   = (int*)((char*)d_ws + cursorOff);
        int*  rowStart = (int*)((char*)d_ws + rowOff);
        int2* perm     = (int2*)((char*)d_ws + permOff);

        // counts (reuse cursor buffer) = 0
        hipMemsetAsync(cursor, 0, (size_t)nNodes * 4, stream);
        hipLaunchKernelGGL(count_kernel, dim3((nE + 255) / 256), dim3(256), 0, stream,
                           ei + nE, cursor, nE);
        hipLaunchKernelGGL(scan_kernel, dim3(1), dim3(1024), 0, stream,
                           cursor, rowStart, cursor, nNodes);
        hipLaunchKernelGGL(permute_kernel, dim3((nE + 255) / 256), dim3(256), 0, stream,
                           ei, cursor, perm, nE);
        hipLaunchKernelGGL(gather_mlp_kernel, dim3(1024), dim3(256), 0, stream,
                           x, ea, perm, rowStart, eps + L,
                           W1L, b1L, W2L, b2L, outp, nNodes);
    } else {
        // fallback: atomic scatter path
        int n4 = nNodes * (DIM / 4);
        hipLaunchKernelGGL(init_agg_kernel, dim3((n4 + 255) / 256), dim3(256), 0, stream,
                           x, eps + L, outp, n4);
        long totalThreads = (long)nE * 16;
        int scatterBlocks = (int)((totalThreads + 255) / 256);
        hipLaunchKernelGGL(scatter_kernel, dim3(scatterBlocks), dim3(256), 0, stream,
                           x, ei, ea, outp, nE);
        hipLaunchKernelGGL(mlp_kernel, dim3(1024), dim3(256), 0, stream,
                           W1L, b1L, W2L, b2L, outp, nNodes);
    }
}

// Round 3
// 338.291 us; speedup vs baseline: 2.2965x; 1.0484x over previous
//
#include <hip/hip_runtime.h>

#define DIM 64

// ---------------- CSR build ----------------

__global__ __launch_bounds__(256)
void count_kernel(const int* __restrict__ dst, int* __restrict__ counts, int nE) {
    int e = blockIdx.x * 256 + threadIdx.x;
    if (e < nE) atomicAdd(&counts[dst[e]], 1);
}

__global__ __launch_bounds__(1024)
void scan_kernel(const int* __restrict__ counts, int* __restrict__ rowStart,
                 int* __restrict__ cursor, int n) {
    __shared__ int part[1024];
    int t = threadIdx.x;
    int chunk = (n + 1023) >> 10;
    int beg = min(t * chunk, n);
    int end = min(beg + chunk, n);
    int s = 0;
    for (int i = beg; i < end; ++i) s += counts[i];
    part[t] = s;
    __syncthreads();
    for (int off = 1; off < 1024; off <<= 1) {
        int v = (t >= off) ? part[t - off] : 0;
        __syncthreads();
        part[t] += v;
        __syncthreads();
    }
    int run = (t == 0) ? 0 : part[t - 1];
    for (int i = beg; i < end; ++i) {
        rowStart[i] = run;
        cursor[i] = run;
        run += counts[i];
    }
    if (t == 0) rowStart[n] = part[1023];
}

__global__ __launch_bounds__(256)
void permute_kernel(const int* __restrict__ ei, int* __restrict__ cursor,
                    int2* __restrict__ perm, int nE) {
    int e = blockIdx.x * 256 + threadIdx.x;
    if (e >= nE) return;
    int s = ei[e];
    int t = ei[nE + e];
    int pos = atomicAdd(&cursor[t], 1);
    perm[pos] = make_int2(s, e);
}

// ---------------- fused gather + MLP ----------------
// Lane layout: grp = lane>>4 (edge slot 0..3), dl = lane&15 (dim quad: dims 4dl..4dl+3).
// Each wave-iteration gathers 4 edges x 16B/lane = 1KB per load instruction.
// Group partials summed via shfl_xor(16|32); MLP reads acc4 via constant-lane shfl
// (v_readlane), no LDS round trip.
__global__ __launch_bounds__(256)
void gather_mlp_kernel(const float4* __restrict__ x4, const float4* __restrict__ ea4,
                       const int2* __restrict__ perm, const int* __restrict__ rowStart,
                       const float* __restrict__ epsL,
                       const float* __restrict__ W1, const float* __restrict__ b1,
                       const float* __restrict__ W2, const float* __restrict__ b2,
                       float* __restrict__ out, int nNodes) {
    __shared__ float sW1[DIM * DIM];
    __shared__ float sW2[DIM * DIM];
    __shared__ float sb1[DIM];
    __shared__ float sb2[DIM];
    for (int i = threadIdx.x; i < DIM * DIM; i += blockDim.x) {
        sW1[i] = W1[i];
        sW2[i] = W2[i];
    }
    if (threadIdx.x < DIM) {
        sb1[threadIdx.x] = b1[threadIdx.x];
        sb2[threadIdx.x] = b2[threadIdx.x];
    }
    __syncthreads();

    const int lane = threadIdx.x & 63;
    const int wave = threadIdx.x >> 6;
    const int grp  = lane >> 4;
    const int dl   = lane & 15;
    const int wavesPerBlock = blockDim.x >> 6;
    const int wavesTotal = gridDim.x * wavesPerBlock;
    const float eps1 = 1.0f + epsL[0];

    for (int node = blockIdx.x * wavesPerBlock + wave; node < nNodes; node += wavesTotal) {
        int beg = rowStart[node];
        int end = rowStart[node + 1];
        float4 acc = make_float4(0.f, 0.f, 0.f, 0.f);

        int j = beg;
        // main: 8 edges per iteration (2 groups of 4), 4KB in flight
        for (; j + 8 <= end; j += 8) {
            int2 pA = perm[j + grp];
            int2 pB = perm[j + grp + 4];
            float4 xa = x4[(long)pA.x * 16 + dl];
            float4 ma = ea4[(long)pA.y * 16 + dl];
            float4 xb = x4[(long)pB.x * 16 + dl];
            float4 mb = ea4[(long)pB.y * 16 + dl];
            acc.x += fmaxf(xa.x + ma.x, 0.f) + fmaxf(xb.x + mb.x, 0.f);
            acc.y += fmaxf(xa.y + ma.y, 0.f) + fmaxf(xb.y + mb.y, 0.f);
            acc.z += fmaxf(xa.z + ma.z, 0.f) + fmaxf(xb.z + mb.z, 0.f);
            acc.w += fmaxf(xa.w + ma.w, 0.f) + fmaxf(xb.w + mb.w, 0.f);
        }
        // remainder: 4 edges per iteration, predicated per lane-group
        for (; j < end; j += 4) {
            int idx = j + grp;
            bool act = idx < end;
            int2 p = perm[act ? idx : beg];
            float4 xv = x4[(long)p.x * 16 + dl];
            float4 m  = ea4[(long)p.y * 16 + dl];
            if (act) {
                acc.x += fmaxf(xv.x + m.x, 0.f);
                acc.y += fmaxf(xv.y + m.y, 0.f);
                acc.z += fmaxf(xv.z + m.z, 0.f);
                acc.w += fmaxf(xv.w + m.w, 0.f);
            }
        }

        // sum the 4 edge-slot groups: xor16 (0<->1, 2<->3), xor32 (0<->2, 1<->3)
        acc.x += __shfl_xor(acc.x, 16); acc.y += __shfl_xor(acc.y, 16);
        acc.z += __shfl_xor(acc.z, 16); acc.w += __shfl_xor(acc.w, 16);
        acc.x += __shfl_xor(acc.x, 32); acc.y += __shfl_xor(acc.y, 32);
        acc.z += __shfl_xor(acc.z, 32); acc.w += __shfl_xor(acc.w, 32);

        // self term (added once, after reduction)
        float4 xs = x4[(long)node * 16 + dl];
        acc.x += eps1 * xs.x; acc.y += eps1 * xs.y;
        acc.z += eps1 * xs.z; acc.w += eps1 * xs.w;

        // GEMM1: o1[lane] = b1 + sum_k h[k] * W1[k][lane]; h[4q+c] = acc.c on lane q
        float o1 = sb1[lane];
        #pragma unroll
        for (int q = 0; q < 16; ++q) {
            float h0 = __shfl(acc.x, q);
            float h1 = __shfl(acc.y, q);
            float h2 = __shfl(acc.z, q);
            float h3 = __shfl(acc.w, q);
            o1 = fmaf(h0, sW1[(4 * q + 0) * DIM + lane], o1);
            o1 = fmaf(h1, sW1[(4 * q + 1) * DIM + lane], o1);
            o1 = fmaf(h2, sW1[(4 * q + 2) * DIM + lane], o1);
            o1 = fmaf(h3, sW1[(4 * q + 3) * DIM + lane], o1);
        }
        float h = fmaxf(o1, 0.f);
        float o2 = sb2[lane];
        #pragma unroll
        for (int k = 0; k < DIM; ++k) {
            o2 = fmaf(__shfl(h, k), sW2[k * DIM + lane], o2);
        }
        out[(long)node * DIM + lane] = fmaxf(o2, 0.f);
    }
}

extern "C" void kernel_launch(void* const* d_in, const int* in_sizes, int n_in,
                              void* d_out, int out_size, void* d_ws, size_t ws_size,
                              hipStream_t stream) {
    const float* x   = (const float*)d_in[0];
    const int*   ei  = (const int*)d_in[1];
    const float* ea  = (const float*)d_in[2];
    const float* W1  = (const float*)d_in[3];
    const float* b1  = (const float*)d_in[4];
    const float* W2  = (const float*)d_in[5];
    const float* b2  = (const float*)d_in[6];
    const float* eps = (const float*)d_in[7];

    const int nNodes  = in_sizes[0] / DIM;
    const int nE      = in_sizes[1] / 2;
    const int nLayers = in_sizes[3] / (DIM * DIM);
    const int L       = nLayers - 1;   // only the last layer affects the output

    const float* W1L = W1 + (long)L * DIM * DIM;
    const float* b1L = b1 + (long)L * DIM;
    const float* W2L = W2 + (long)L * DIM * DIM;
    const float* b2L = b2 + (long)L * DIM;
    float* outp = (float*)d_out;

    // ws layout: cursor[int N] | rowStart[int N+1] | pad | perm[int2 E]
    size_t rowOff  = (size_t)nNodes * 4;
    size_t permOff = ((rowOff + (size_t)(nNodes + 1) * 4 + 7) / 8) * 8;

    int*  cursor   = (int*)d_ws;
    int*  rowStart = (int*)((char*)d_ws + rowOff);
    int2* perm     = (int2*)((char*)d_ws + permOff);

    hipMemsetAsync(cursor, 0, (size_t)nNodes * 4, stream);
    hipLaunchKernelGGL(count_kernel, dim3((nE + 255) / 256), dim3(256), 0, stream,
                       ei + nE, cursor, nE);
    hipLaunchKernelGGL(scan_kernel, dim3(1), dim3(1024), 0, stream,
                       cursor, rowStart, cursor, nNodes);
    hipLaunchKernelGGL(permute_kernel, dim3((nE + 255) / 256), dim3(256), 0, stream,
                       ei, cursor, perm, nE);
    hipLaunchKernelGGL(gather_mlp_kernel, dim3(1024), dim3(256), 0, stream,
                       (const float4*)x, (const float4*)ea, perm, rowStart, eps + L,
                       W1L, b1L, W2L, b2L, outp, nNodes);
}